// Round 1
// baseline (6816.731 us; speedup 1.0000x reference)
//
#include <hip/hip_runtime.h>
#include <stdint.h>

// ---------------- types & helpers ----------------
typedef __attribute__((ext_vector_type(4))) float  f32x4;
typedef __attribute__((ext_vector_type(8))) short  s16x8;
typedef __attribute__((ext_vector_type(4))) short  s16x4;
typedef __attribute__((ext_vector_type(8))) __bf16 bf16x8;

#define DEV __device__ __forceinline__

DEV float b2f(short h) {
  unsigned u = ((unsigned)(unsigned short)h) << 16;
  return __builtin_bit_cast(float, u);
}
DEV short f2b(float f) {
  unsigned u = __builtin_bit_cast(unsigned, f);
  u = (u + 0x7FFFu + ((u >> 16) & 1u)) >> 16;
  return (short)u;
}
DEV float fsig(float x) { return 1.0f / (1.0f + __expf(-x)); }
DEV float ftanh(float x) {
  x = fminf(fmaxf(x, -15.0f), 15.0f);
  float e = __expf(2.0f * x);
  return (e - 1.0f) / (e + 1.0f);
}
DEV float fsp(float x) { return (x > 20.0f) ? x : __logf(1.0f + __expf(x)); }

DEV f32x4 MFMA(s16x8 a, s16x8 b, f32x4 c) {
  return __builtin_amdgcn_mfma_f32_16x16x32_bf16(
      __builtin_bit_cast(bf16x8, a), __builtin_bit_cast(bf16x8, b), c, 0, 0, 0);
}
DEV void gload16(const void* g, void* l) {
  __builtin_amdgcn_global_load_lds(
      (const __attribute__((address_space(1))) unsigned*)g,
      (__attribute__((address_space(3))) unsigned*)l, 16, 0, 0);
}

// ---------------- fp32 -> bf16 converts ----------------
__global__ void k_f2b(const float* __restrict__ s, short* __restrict__ d, int n) {
  int i = (blockIdx.x * 256 + threadIdx.x) * 4;
  if (i >= n) return;
  float4 v = *(const float4*)(s + i);
  s16x4 o; o[0] = f2b(v.x); o[1] = f2b(v.y); o[2] = f2b(v.z); o[3] = f2b(v.w);
  *(s16x4*)(d + i) = o;
}

// strided slice convert: dst[r][c] = src[r*sstr + soff + c], c in [0, cols)
__global__ void k_f2bs(const float* __restrict__ s, short* __restrict__ d,
                       int cols, int sstr, int soff, int total) {
  int i = (blockIdx.x * 256 + threadIdx.x) * 4;
  if (i >= total) return;
  int r = i / cols, c = i - r * cols;
  float4 v = *(const float4*)(s + (size_t)r * sstr + soff + c);
  s16x4 o; o[0] = f2b(v.x); o[1] = f2b(v.y); o[2] = f2b(v.z); o[3] = f2b(v.w);
  *(s16x4*)(d + i) = o;
}

// ---------------- generic bf16 MFMA GEMM, 128x128 tile, BK=64 ----------------
// C[M,N] = A[M,K] @ W[N,K]^T (+bias). EPI: 0=f32 store, 1=relu->bf16,
// 2=bf16 transposed-tile store dst[(bm*N+col)*128+rlocal], 3=tanh->f32 + bf16 hB-blocked.
template <int EPI>
__global__ __launch_bounds__(256) void kgemm(
    const short* __restrict__ A, const short* __restrict__ W,
    const float* __restrict__ bias, float* __restrict__ outF,
    short* __restrict__ outB, int M, int N, int K) {
  __shared__ short lA[8192];
  __shared__ short lB[8192];
  const int tid = threadIdx.x, lane = tid & 63, wid = tid >> 6;
  const int l15 = lane & 15, lq = lane >> 4;
  const int m0 = blockIdx.x * 128, n0 = blockIdx.y * 128;
  const int wr2 = wid >> 1, wc2 = wid & 1;
  const f32x4 vz = {0.f, 0.f, 0.f, 0.f};
  f32x4 acc[4][4];
#pragma unroll
  for (int i = 0; i < 4; ++i)
#pragma unroll
    for (int j = 0; j < 4; ++j) acc[i][j] = vz;
  const int Kb = K * 2;
  const int nkt = K >> 6;
  const int srow = lane >> 3, sk = (lane & 7) * 16;
  const char* gA = (const char*)A;
  const char* gW = (const char*)W;
  for (int kt = 0; kt < nkt; ++kt) {
    __syncthreads();
#pragma unroll
    for (int i = 0; i < 4; ++i) {
      const int c = wid * 4 + i;
      gload16(gA + (size_t)(m0 + c * 8 + srow) * Kb + kt * 128 + sk, (char*)lA + c * 1024);
      gload16(gW + (size_t)(n0 + c * 8 + srow) * Kb + kt * 128 + sk, (char*)lB + c * 1024);
    }
    __syncthreads();
#pragma unroll
    for (int kc = 0; kc < 2; ++kc) {
      s16x8 af[4], bf[4];
#pragma unroll
      for (int mt = 0; mt < 4; ++mt)
        af[mt] = *(const s16x8*)((const char*)lA + (wr2 * 64 + mt * 16 + l15) * 128 + kc * 64 + lq * 16);
#pragma unroll
      for (int nt = 0; nt < 4; ++nt)
        bf[nt] = *(const s16x8*)((const char*)lB + (wc2 * 64 + nt * 16 + l15) * 128 + kc * 64 + lq * 16);
#pragma unroll
      for (int mt = 0; mt < 4; ++mt)
#pragma unroll
        for (int nt = 0; nt < 4; ++nt)
          acc[mt][nt] = MFMA(af[mt], bf[nt], acc[mt][nt]);
    }
  }
#pragma unroll
  for (int mt = 0; mt < 4; ++mt) {
#pragma unroll
    for (int nt = 0; nt < 4; ++nt) {
      const int col = n0 + wc2 * 64 + nt * 16 + l15;
      const int rl = wr2 * 64 + mt * 16 + lq * 4;
      const int row = m0 + rl;
      const float bv = bias ? bias[col] : 0.f;
      if (EPI == 0) {
#pragma unroll
        for (int d = 0; d < 4; ++d) outF[(size_t)(row + d) * N + col] = acc[mt][nt][d] + bv;
      } else if (EPI == 1) {
#pragma unroll
        for (int d = 0; d < 4; ++d) {
          float v = acc[mt][nt][d] + bv;
          v = v > 0.f ? v : 0.f;
          outB[(size_t)(row + d) * N + col] = f2b(v);
        }
      } else if (EPI == 2) {
        s16x4 pk;
#pragma unroll
        for (int d = 0; d < 4; ++d) pk[d] = f2b(acc[mt][nt][d] + bv);
        *(s16x4*)(outB + ((size_t)blockIdx.x * N + col) * 128 + rl) = pk;
      } else {
#pragma unroll
        for (int d = 0; d < 4; ++d) {
          float v = ftanh(acc[mt][nt][d] + bv);
          outF[(size_t)(row + d) * N + col] = v;
          outB[((size_t)(col >> 3) * 128 + (row + d)) * 8 + (col & 7)] = f2b(v);
        }
      }
    }
  }
}

// ---------------- persistent encoder scan (fwd + bwd GRU) ----------------
// 64 WGs x 256 thr. WG w: gru=w>>5, bg=(w&31)>>3 (batch group of 32), cw=w&7.
// wave wid: col-tile ct=cw*4+wid -> h-cols [ct*16, ct*16+16). Weight-stationary regs.
// hB layout per gru: [2 parity][64 kc8][128 b][8] bf16.
__global__ __launch_bounds__(256, 1) void enc_scan(
    const short* __restrict__ xpTf, const short* __restrict__ xpTb,
    const short* __restrict__ Whf, const short* __restrict__ Whb,
    const float* __restrict__ bhf, const float* __restrict__ bhb,
    short* __restrict__ hB, short* __restrict__ ench, unsigned* __restrict__ ctrs) {
  const int tid = threadIdx.x, lane = tid & 63, wid = tid >> 6;
  const int l15 = lane & 15, lq = lane >> 4;
  const int w = blockIdx.x;
  const int gru = w >> 5, rr = w & 31, bg = rr >> 3, cw = rr & 7;
  const int J0 = (cw * 4 + wid) * 16, b0 = bg * 32;
  const short* Wg = gru ? Whb : Whf;
  const float* bb = gru ? bhb : bhf;
  const short* xpT = gru ? xpTb : xpTf;
  short* hBg = hB + (size_t)gru * 131072;
  unsigned* ctr = ctrs + (gru * 4 + bg);
  const f32x4 vz = {0.f, 0.f, 0.f, 0.f};

  s16x8 wfr[3][16];
#pragma unroll
  for (int g = 0; g < 3; ++g) {
    const short* wrp = Wg + (size_t)(g * 512 + J0 + l15) * 512 + lq * 8;
#pragma unroll
    for (int kc = 0; kc < 16; ++kc) wfr[g][kc] = *(const s16x8*)(wrp + kc * 32);
  }
  float bi[3][4];
#pragma unroll
  for (int g = 0; g < 3; ++g)
#pragma unroll
    for (int d = 0; d < 4; ++d) bi[g][d] = bb[g * 512 + J0 + lq * 4 + d];
  float hpv[2][4];
#pragma unroll
  for (int nt = 0; nt < 2; ++nt)
#pragma unroll
    for (int d = 0; d < 4; ++d) hpv[nt][d] = 0.f;

  for (int t = 0; t < 192; ++t) {
    f32x4 acc[3][2];
#pragma unroll
    for (int g = 0; g < 3; ++g)
#pragma unroll
      for (int nt = 0; nt < 2; ++nt) acc[g][nt] = vz;
    if (t > 0) {
      const short* hsrc = hBg + ((t + 1) & 1) * 65536;
#pragma unroll
      for (int kc = 0; kc < 16; ++kc) {
        const int cb = (kc * 4 + lq) * 128 + b0 + l15;
        s16x8 f0 = *(const s16x8*)(hsrc + (size_t)cb * 8);
        s16x8 f1 = *(const s16x8*)(hsrc + (size_t)(cb + 16) * 8);
#pragma unroll
        for (int g = 0; g < 3; ++g) {
          acc[g][0] = MFMA(wfr[g][kc], f0, acc[g][0]);
          acc[g][1] = MFMA(wfr[g][kc], f1, acc[g][1]);
        }
      }
    }
    const int tt = gru ? (191 - t) : t;
    short* hdst = hBg + (t & 1) * 65536;
    const short* xb = xpT + (size_t)tt * 1536 * 128;
#pragma unroll
    for (int nt = 0; nt < 2; ++nt) {
      const int b = b0 + nt * 16 + l15;
      s16x4 pk;
#pragma unroll
      for (int d = 0; d < 4; ++d) {
        const int ch = J0 + lq * 4 + d;
        float xr = b2f(xb[(size_t)ch * 128 + b]);
        float xz = b2f(xb[(size_t)(512 + ch) * 128 + b]);
        float xn = b2f(xb[(size_t)(1024 + ch) * 128 + b]);
        float hr = acc[0][nt][d] + bi[0][d];
        float hz = acc[1][nt][d] + bi[1][d];
        float hn = acc[2][nt][d] + bi[2][d];
        float rg = fsig(xr + hr);
        float zg = fsig(xz + hz);
        float nn = ftanh(xn + rg * hn);
        float hv = (1.f - zg) * nn + zg * hpv[nt][d];
        hpv[nt][d] = hv;
        pk[d] = f2b(hv);
      }
      const int chb = J0 + lq * 4;
      *(s16x4*)(hdst + (((size_t)((chb >> 3) * 128 + b)) << 3) + (chb & 7)) = pk;
      if (t == 191) *(s16x4*)(ench + (size_t)gru * 65536 + (size_t)b * 512 + chb) = pk;
    }
    __threadfence();
    __syncthreads();
    if (tid == 0) {
      __hip_atomic_fetch_add(ctr, 1u, __ATOMIC_RELEASE, __HIP_MEMORY_SCOPE_AGENT);
      const unsigned tgt = 8u * (unsigned)(t + 1);
      unsigned gd = 0;
      while (__hip_atomic_load(ctr, __ATOMIC_ACQUIRE, __HIP_MEMORY_SCOPE_AGENT) < tgt) {
        if (++gd > (1u << 24)) break;  // safety: avoid infinite hang
      }
    }
    __syncthreads();
  }
}

// ---------------- persistent decoder scan ----------------
// 64 WGs x 256 thr. WG w: bg=w>>4 (batch group of 32), w4=w&15.
// wave wid: pairi=wid>>1 -> col-tile ct=w4*2+pairi; role=wid&1 (0: Whh_d, 1: W_s).
__global__ __launch_bounds__(256, 1) void dec_scan(
    const short* __restrict__ zpT, const short* __restrict__ Whd,
    const short* __restrict__ Wsd, const float* __restrict__ bhd,
    const float* __restrict__ h0f, short* __restrict__ hB,
    short* __restrict__ Hs, unsigned* __restrict__ ctrs) {
  const int tid = threadIdx.x, lane = tid & 63, wid = tid >> 6;
  const int l15 = lane & 15, lq = lane >> 4;
  const int w = blockIdx.x;
  const int bg = w >> 4, w4 = w & 15;
  const int pairi = wid >> 1, role = wid & 1;
  const int J0 = (w4 * 2 + pairi) * 16, b0 = bg * 32;
  unsigned* ctr = ctrs + 8 + bg;
  __shared__ float lxs[2][3][16][32];
  const short* Wg = role ? Wsd : Whd;
  const f32x4 vz = {0.f, 0.f, 0.f, 0.f};

  s16x8 wfr[3][16];
#pragma unroll
  for (int g = 0; g < 3; ++g) {
    const short* wrp = Wg + (size_t)(g * 512 + J0 + l15) * 512 + lq * 8;
#pragma unroll
    for (int kc = 0; kc < 16; ++kc) wfr[g][kc] = *(const s16x8*)(wrp + kc * 32);
  }
  float bi[3][4];
  float hpv[2][4];
#pragma unroll
  for (int g = 0; g < 3; ++g)
#pragma unroll
    for (int d = 0; d < 4; ++d)
      bi[g][d] = (role == 0) ? bhd[g * 512 + J0 + lq * 4 + d] : 0.f;
#pragma unroll
  for (int nt = 0; nt < 2; ++nt)
#pragma unroll
    for (int d = 0; d < 4; ++d)
      hpv[nt][d] = (role == 0) ? h0f[(size_t)(b0 + nt * 16 + l15) * 512 + J0 + lq * 4 + d] : 0.f;

  for (int t = 0; t < 192; ++t) {
    f32x4 acc[3][2];
#pragma unroll
    for (int g = 0; g < 3; ++g)
#pragma unroll
      for (int nt = 0; nt < 2; ++nt) acc[g][nt] = vz;
    if (t > 0 || role == 0) {  // at t=0: s=0 so W_s waves skip; h=dec_h0 prefilled in hB[1]
      const short* hsrc = hB + ((t + 1) & 1) * 65536;
#pragma unroll
      for (int kc = 0; kc < 16; ++kc) {
        const int cb = (kc * 4 + lq) * 128 + b0 + l15;
        s16x8 f0 = *(const s16x8*)(hsrc + (size_t)cb * 8);
        s16x8 f1 = *(const s16x8*)(hsrc + (size_t)(cb + 16) * 8);
#pragma unroll
        for (int g = 0; g < 3; ++g) {
          acc[g][0] = MFMA(wfr[g][kc], f0, acc[g][0]);
          acc[g][1] = MFMA(wfr[g][kc], f1, acc[g][1]);
        }
      }
    }
    if (role == 1) {
#pragma unroll
      for (int g = 0; g < 3; ++g)
#pragma unroll
        for (int nt = 0; nt < 2; ++nt)
#pragma unroll
          for (int d = 0; d < 4; ++d)
            lxs[pairi][g][lq * 4 + d][nt * 16 + l15] = acc[g][nt][d];
    }
    __syncthreads();
    if (role == 0) {
      short* hdst = hB + (t & 1) * 65536;
#pragma unroll
      for (int nt = 0; nt < 2; ++nt) {
        const int b = b0 + nt * 16 + l15;
        s16x4 pk;
#pragma unroll
        for (int d = 0; d < 4; ++d) {
          const int chl = lq * 4 + d, ch = J0 + chl;
          float xr = b2f(zpT[(size_t)ch * 128 + b]) + lxs[pairi][0][chl][nt * 16 + l15];
          float xz = b2f(zpT[(size_t)(512 + ch) * 128 + b]) + lxs[pairi][1][chl][nt * 16 + l15];
          float xn = b2f(zpT[(size_t)(1024 + ch) * 128 + b]) + lxs[pairi][2][chl][nt * 16 + l15];
          float hr = acc[0][nt][d] + bi[0][d];
          float hz = acc[1][nt][d] + bi[1][d];
          float hn = acc[2][nt][d] + bi[2][d];
          float rg = fsig(xr + hr);
          float zg = fsig(xz + hz);
          float nn = ftanh(xn + rg * hn);
          float hv = (1.f - zg) * nn + zg * hpv[nt][d];
          hpv[nt][d] = hv;
          pk[d] = f2b(hv);
        }
        const int chb = J0 + lq * 4;
        *(s16x4*)(hdst + (((size_t)((chb >> 3) * 128 + b)) << 3) + (chb & 7)) = pk;
        *(s16x4*)(Hs + (size_t)(t * 128 + b) * 512 + chb) = pk;
      }
    }
    __threadfence();
    __syncthreads();
    if (tid == 0) {
      __hip_atomic_fetch_add(ctr, 1u, __ATOMIC_RELEASE, __HIP_MEMORY_SCOPE_AGENT);
      const unsigned tgt = 16u * (unsigned)(t + 1);
      unsigned gd = 0;
      while (__hip_atomic_load(ctr, __ATOMIC_ACQUIRE, __HIP_MEMORY_SCOPE_AGENT) < tgt) {
        if (++gd > (1u << 24)) break;
      }
    }
    __syncthreads();
  }
}

// ---------------- latent elementwise ----------------
__global__ void k_latent(const float* __restrict__ tmp, const float* __restrict__ b_mean,
                         const float* __restrict__ b_std, const float* __restrict__ eps_z,
                         float* __restrict__ out, short* __restrict__ zexp) {
  int i = blockIdx.x * 256 + threadIdx.x;
  if (i >= 32768) return;
  int c = i & 127, b = (i >> 7) & 127, g = i >> 14;
  float mp = tmp[(size_t)(g * 128 + b) * 256 + c] + b_mean[c];
  float sp = fsp(tmp[(size_t)(g * 128 + b) * 256 + 128 + c] + b_std[c]);
  float zv = eps_z[i] * sp + mp;
  out[i] = mp;
  out[32768 + i] = sp;
  out[65536 + i] = zv;
  zexp[b * 256 + g * 128 + c] = f2b(zv);
}

// ---------------- outputs elementwise ----------------
__global__ void k_preds(const float* __restrict__ tmp2, const float* __restrict__ b_dm,
                        const float* __restrict__ b_ds, const float* __restrict__ eps_y,
                        float* __restrict__ out) {
  int j = blockIdx.x * 256 + threadIdx.x;
  if (j >= 1572864) return;
  int c = j & 63;
  int row = j >> 6;
  float m = fsp(tmp2[(size_t)row * 128 + c] + b_dm[c]);
  float st = fsp(tmp2[(size_t)row * 128 + 64 + c] + b_ds[c]);
  out[98304 + j] = eps_y[j] * st + m;
  out[1671168 + j] = m;
  out[3244032 + j] = st;
}

// ---------------- launch ----------------
extern "C" void kernel_launch(void* const* d_in, const int* in_sizes, int n_in,
                              void* d_out, int out_size, void* d_ws, size_t ws_size,
                              hipStream_t stream) {
  (void)in_sizes; (void)n_in; (void)out_size; (void)ws_size;
  const float* x      = (const float*)d_in[0];
  const float* eps_z  = (const float*)d_in[2];
  const float* eps_y  = (const float*)d_in[3];
  const float* W_phi1 = (const float*)d_in[4];
  const float* b_phi1 = (const float*)d_in[5];
  const float* W_phi2 = (const float*)d_in[6];
  const float* b_phi2 = (const float*)d_in[7];
  const float* Wih_ef = (const float*)d_in[8];
  const float* bih_ef = (const float*)d_in[9];
  const float* Whh_ef = (const float*)d_in[10];
  const float* bhh_ef = (const float*)d_in[11];
  const float* Wih_eb = (const float*)d_in[12];
  const float* bih_eb = (const float*)d_in[13];
  const float* Whh_eb = (const float*)d_in[14];
  const float* bhh_eb = (const float*)d_in[15];
  const float* W_mean = (const float*)d_in[16];
  const float* b_mean = (const float*)d_in[17];
  const float* W_std  = (const float*)d_in[18];
  const float* b_std  = (const float*)d_in[19];
  const float* W_fh   = (const float*)d_in[20];
  const float* b_fh   = (const float*)d_in[21];
  const float* Wih_d  = (const float*)d_in[22];
  const float* bih_d  = (const float*)d_in[23];
  const float* Whh_d  = (const float*)d_in[24];
  const float* bhh_d  = (const float*)d_in[25];
  const float* W_dm   = (const float*)d_in[26];
  const float* b_dm   = (const float*)d_in[27];
  const float* W_ds   = (const float*)d_in[28];
  const float* b_ds   = (const float*)d_in[29];
  float* out = (float*)d_out;
  char* ws = (char*)d_ws;

  // workspace layout (bytes). Hs aliases x16+C1; tmp2 aliases phi (dead by then).
  short* x16  = (short*)(ws + 0);
  short* C1   = (short*)(ws + 6291456);
  short* Hs   = (short*)(ws + 0);
  short* phi  = (short*)(ws + 31457280);
  float* tmp2 = (float*)(ws + 31457280);
  short* xpf  = (short*)(ws + 56623104);
  short* xpb  = (short*)(ws + 132120576);
  char*  wb   = ws + 207618048;
  short* w_phi1_16 = (short*)(wb + 0);
  short* w_phi2_16 = (short*)(wb + 131072);
  short* w_ihef = (short*)(wb + 655360);
  short* w_hhef = (short*)(wb + 2228224);
  short* w_iheb = (short*)(wb + 3801088);
  short* w_hheb = (short*)(wb + 5373952);
  short* w_ms   = (short*)(wb + 6946816);
  short* w_fh   = (short*)(wb + 7208960);
  short* w_z    = (short*)(wb + 7471104);
  short* w_s    = (short*)(wb + 8257536);
  short* w_hhd  = (short*)(wb + 9830400);
  short* w_out  = (short*)(wb + 11403264);
  short* hBe   = (short*)(ws + 219152384);
  short* ench  = (short*)(ws + 219676672);
  float* tmpms = (float*)(ws + 219938816);
  short* zexp  = (short*)(ws + 220200960);
  float* h0f   = (float*)(ws + 220266496);
  short* hBd   = (short*)(ws + 220528640);
  short* zpT   = (short*)(ws + 220790784);
  unsigned* ctr = (unsigned*)(ws + 221184000);

  hipMemsetAsync(ctr, 0, 256, stream);

  // weight/input converts to bf16
  k_f2b<<<3072, 256, 0, stream>>>(x, x16, 3145728);
  k_f2b<<<64,   256, 0, stream>>>(W_phi1, w_phi1_16, 65536);
  k_f2b<<<256,  256, 0, stream>>>(W_phi2, w_phi2_16, 262144);
  k_f2b<<<768,  256, 0, stream>>>(Wih_ef, w_ihef, 786432);
  k_f2b<<<768,  256, 0, stream>>>(Whh_ef, w_hhef, 786432);
  k_f2b<<<768,  256, 0, stream>>>(Wih_eb, w_iheb, 786432);
  k_f2b<<<768,  256, 0, stream>>>(Whh_eb, w_hheb, 786432);
  k_f2b<<<64,   256, 0, stream>>>(W_mean, w_ms, 65536);
  k_f2b<<<64,   256, 0, stream>>>(W_std,  w_ms + 65536, 65536);
  k_f2b<<<128,  256, 0, stream>>>(W_fh, w_fh, 131072);
  k_f2b<<<768,  256, 0, stream>>>(Whh_d, w_hhd, 786432);
  k_f2b<<<32,   256, 0, stream>>>(W_dm, w_out, 32768);
  k_f2b<<<32,   256, 0, stream>>>(W_ds, w_out + 32768, 32768);
  k_f2bs<<<384, 256, 0, stream>>>(Wih_d, w_z, 256, 768, 0, 393216);
  k_f2bs<<<768, 256, 0, stream>>>(Wih_d, w_s, 512, 768, 256, 786432);

  // phi MLP
  kgemm<1><<<dim3(192, 4), 256, 0, stream>>>(x16, w_phi1_16, b_phi1, (float*)nullptr, C1, 24576, 512, 128);
  kgemm<1><<<dim3(192, 4), 256, 0, stream>>>(C1, w_phi2_16, b_phi2, (float*)nullptr, phi, 24576, 512, 512);
  // x-projections (transposed-tile bf16 stores)
  kgemm<2><<<dim3(192, 12), 256, 0, stream>>>(phi, w_ihef, bih_ef, (float*)nullptr, xpf, 24576, 1536, 512);
  kgemm<2><<<dim3(192, 12), 256, 0, stream>>>(phi, w_iheb, bih_eb, (float*)nullptr, xpb, 24576, 1536, 512);
  // encoder scans (fwd + bwd concurrent)
  enc_scan<<<64, 256, 0, stream>>>(xpf, xpb, w_hhef, w_hheb, bhh_ef, bhh_eb, hBe, ench, ctr);
  // latent
  kgemm<0><<<dim3(2, 2), 256, 0, stream>>>(ench, w_ms, (const float*)nullptr, tmpms, (short*)nullptr, 256, 256, 512);
  k_latent<<<128, 256, 0, stream>>>(tmpms, b_mean, b_std, eps_z, out, zexp);
  // decoder init: dec_h0 (f32 + blocked bf16 into hBd parity 1), z_proj (transposed bf16)
  kgemm<3><<<dim3(1, 4), 256, 0, stream>>>(zexp, w_fh, b_fh, h0f, hBd + 65536, 128, 512, 256);
  kgemm<2><<<dim3(1, 12), 256, 0, stream>>>(zexp, w_z, bih_d, (float*)nullptr, zpT, 128, 1536, 256);
  // decoder scan
  dec_scan<<<64, 256, 0, stream>>>(zpT, w_hhd, w_s, bhh_d, h0f, hBd, Hs, ctr);
  // output head
  kgemm<0><<<dim3(192, 1), 256, 0, stream>>>(Hs, w_out, (const float*)nullptr, tmp2, (short*)nullptr, 24576, 128, 512);
  k_preds<<<6144, 256, 0, stream>>>(tmp2, b_dm, b_ds, eps_y, out);
}

// Round 3
// 3466.538 us; speedup vs baseline: 1.9664x; 1.9664x over previous
//
#include <hip/hip_runtime.h>
#include <stdint.h>

// ---------------- types & helpers ----------------
typedef __attribute__((ext_vector_type(4))) float  f32x4;
typedef __attribute__((ext_vector_type(8))) short  s16x8;
typedef __attribute__((ext_vector_type(4))) short  s16x4;
typedef __attribute__((ext_vector_type(8))) __bf16 bf16x8;

#define DEV __device__ __forceinline__

DEV float b2f(short h) {
  unsigned u = ((unsigned)(unsigned short)h) << 16;
  return __builtin_bit_cast(float, u);
}
DEV short f2b(float f) {
  unsigned u = __builtin_bit_cast(unsigned, f);
  u = (u + 0x7FFFu + ((u >> 16) & 1u)) >> 16;
  return (short)u;
}
DEV float fsig(float x) { return 1.0f / (1.0f + __expf(-x)); }
DEV float ftanh(float x) {
  x = fminf(fmaxf(x, -15.0f), 15.0f);
  float e = __expf(2.0f * x);
  return (e - 1.0f) / (e + 1.0f);
}
DEV float fsp(float x) { return (x > 20.0f) ? x : __logf(1.0f + __expf(x)); }

DEV f32x4 MFMA(s16x8 a, s16x8 b, f32x4 c) {
  return __builtin_amdgcn_mfma_f32_16x16x32_bf16(
      __builtin_bit_cast(bf16x8, a), __builtin_bit_cast(bf16x8, b), c, 0, 0, 0);
}
DEV void gload16(const void* g, void* l) {
  __builtin_amdgcn_global_load_lds(
      (const __attribute__((address_space(1))) unsigned*)g,
      (__attribute__((address_space(3))) unsigned*)l, 16, 0, 0);
}

// ---- cross-XCD coherent accesses: explicit sc0 sc1 (bypass L1+L2, hit LLC) ----
DEV s16x8 load_coh16(const short* p) {
  s16x8 r;
  asm volatile("global_load_dwordx4 %0, %1, off sc0 sc1" : "=v"(r) : "v"(p) : "memory");
  return r;
}
DEV void store_coh8(short* p, s16x4 v) {
  asm volatile("global_store_dwordx2 %0, %1, off sc0 sc1" :: "v"(p), "v"(v) : "memory");
}
DEV unsigned load_coh4_wait(const unsigned* p) {
  unsigned r;
  asm volatile("global_load_dword %0, %1, off sc0 sc1\n\ts_waitcnt vmcnt(0)"
               : "=v"(r) : "v"(p) : "memory");
  return r;
}

// cooperative stage of h slice: global [64 kc8][128 b][8sh] (b0..b0+31) -> lds [64][32][8sh]
// 2048 cells x 16B; 8 iters x 256 threads.
DEV void stage_h(const short* __restrict__ hsrc, short* __restrict__ lds_h, int b0, int tid) {
  s16x8 tmp[8];
#pragma unroll
  for (int it = 0; it < 8; ++it) {
    const int idx = it * 256 + tid;  // 0..2047
    const int kc8 = idx >> 5, bb = idx & 31;
    tmp[it] = load_coh16(hsrc + ((size_t)(kc8 * 128 + b0 + bb) << 3));
  }
  asm volatile("s_waitcnt vmcnt(0)" ::: "memory");
  __builtin_amdgcn_sched_barrier(0);
#pragma unroll
  for (int it = 0; it < 8; ++it) {
    const int idx = it * 256 + tid;
    const int kc8 = idx >> 5, bb = idx & 31;
    *(s16x8*)(lds_h + ((size_t)(kc8 * 32 + bb) << 3)) = tmp[it];
  }
}

// group barrier: drain own (sc1) stores, arrive via coherent RMW, poll via sc1 load
DEV void group_barrier(unsigned* ctr, unsigned tgt) {
  asm volatile("s_waitcnt vmcnt(0)" ::: "memory");
  __syncthreads();
  if (threadIdx.x == 0) {
    __hip_atomic_fetch_add(ctr, 1u, __ATOMIC_RELAXED, __HIP_MEMORY_SCOPE_AGENT);
    unsigned gd = 0;
    while (load_coh4_wait(ctr) < tgt) {
      if (++gd > (1u << 18)) break;  // deadlock escape; never hit in normal operation
    }
  }
  __syncthreads();
}

// ---------------- fp32 -> bf16 converts ----------------
__global__ void k_f2b(const float* __restrict__ s, short* __restrict__ d, int n) {
  int i = (blockIdx.x * 256 + threadIdx.x) * 4;
  if (i >= n) return;
  float4 v = *(const float4*)(s + i);
  s16x4 o; o[0] = f2b(v.x); o[1] = f2b(v.y); o[2] = f2b(v.z); o[3] = f2b(v.w);
  *(s16x4*)(d + i) = o;
}

__global__ void k_f2bs(const float* __restrict__ s, short* __restrict__ d,
                       int cols, int sstr, int soff, int total) {
  int i = (blockIdx.x * 256 + threadIdx.x) * 4;
  if (i >= total) return;
  int r = i / cols, c = i - r * cols;
  float4 v = *(const float4*)(s + (size_t)r * sstr + soff + c);
  s16x4 o; o[0] = f2b(v.x); o[1] = f2b(v.y); o[2] = f2b(v.z); o[3] = f2b(v.w);
  *(s16x4*)(d + i) = o;
}

// ---------------- generic bf16 MFMA GEMM, 128x128 tile, BK=64 ----------------
template <int EPI>
__global__ __launch_bounds__(256) void kgemm(
    const short* __restrict__ A, const short* __restrict__ W,
    const float* __restrict__ bias, float* __restrict__ outF,
    short* __restrict__ outB, int M, int N, int K) {
  __shared__ short lA[8192];
  __shared__ short lB[8192];
  const int tid = threadIdx.x, lane = tid & 63, wid = tid >> 6;
  const int l15 = lane & 15, lq = lane >> 4;
  const int m0 = blockIdx.x * 128, n0 = blockIdx.y * 128;
  const int wr2 = wid >> 1, wc2 = wid & 1;
  const f32x4 vz = {0.f, 0.f, 0.f, 0.f};
  f32x4 acc[4][4];
#pragma unroll
  for (int i = 0; i < 4; ++i)
#pragma unroll
    for (int j = 0; j < 4; ++j) acc[i][j] = vz;
  const int Kb = K * 2;
  const int nkt = K >> 6;
  const int srow = lane >> 3, sk = (lane & 7) * 16;
  const char* gA = (const char*)A;
  const char* gW = (const char*)W;
  for (int kt = 0; kt < nkt; ++kt) {
    __syncthreads();
#pragma unroll
    for (int i = 0; i < 4; ++i) {
      const int c = wid * 4 + i;
      gload16(gA + (size_t)(m0 + c * 8 + srow) * Kb + kt * 128 + sk, (char*)lA + c * 1024);
      gload16(gW + (size_t)(n0 + c * 8 + srow) * Kb + kt * 128 + sk, (char*)lB + c * 1024);
    }
    __syncthreads();
#pragma unroll
    for (int kc = 0; kc < 2; ++kc) {
      s16x8 af[4], bf[4];
#pragma unroll
      for (int mt = 0; mt < 4; ++mt)
        af[mt] = *(const s16x8*)((const char*)lA + (wr2 * 64 + mt * 16 + l15) * 128 + kc * 64 + lq * 16);
#pragma unroll
      for (int nt = 0; nt < 4; ++nt)
        bf[nt] = *(const s16x8*)((const char*)lB + (wc2 * 64 + nt * 16 + l15) * 128 + kc * 64 + lq * 16);
#pragma unroll
      for (int mt = 0; mt < 4; ++mt)
#pragma unroll
        for (int nt = 0; nt < 4; ++nt)
          acc[mt][nt] = MFMA(af[mt], bf[nt], acc[mt][nt]);
    }
  }
#pragma unroll
  for (int mt = 0; mt < 4; ++mt) {
#pragma unroll
    for (int nt = 0; nt < 4; ++nt) {
      const int col = n0 + wc2 * 64 + nt * 16 + l15;
      const int rl = wr2 * 64 + mt * 16 + lq * 4;
      const int row = m0 + rl;
      const float bv = bias ? bias[col] : 0.f;
      if (EPI == 0) {
#pragma unroll
        for (int d = 0; d < 4; ++d) outF[(size_t)(row + d) * N + col] = acc[mt][nt][d] + bv;
      } else if (EPI == 1) {
#pragma unroll
        for (int d = 0; d < 4; ++d) {
          float v = acc[mt][nt][d] + bv;
          v = v > 0.f ? v : 0.f;
          outB[(size_t)(row + d) * N + col] = f2b(v);
        }
      } else if (EPI == 2) {
        s16x4 pk;
#pragma unroll
        for (int d = 0; d < 4; ++d) pk[d] = f2b(acc[mt][nt][d] + bv);
        *(s16x4*)(outB + ((size_t)blockIdx.x * N + col) * 128 + rl) = pk;
      } else {
#pragma unroll
        for (int d = 0; d < 4; ++d) {
          float v = ftanh(acc[mt][nt][d] + bv);
          outF[(size_t)(row + d) * N + col] = v;
          outB[((size_t)(col >> 3) * 128 + (row + d)) * 8 + (col & 7)] = f2b(v);
        }
      }
    }
  }
}

// ---------------- persistent encoder scan (fwd + bwd GRU) ----------------
// 64 WGs x 256 thr. WG w: gru=w>>5, bg=(w&31)>>3, cw=w&7. Wave wid: col-tile cw*4+wid.
// h exchange through LLC via sc0 sc1 accesses; per-step LDS staging of the 32-batch slice.
__global__ __launch_bounds__(256, 1) void enc_scan(
    const short* __restrict__ xpTf, const short* __restrict__ xpTb,
    const short* __restrict__ Whf, const short* __restrict__ Whb,
    const float* __restrict__ bhf, const float* __restrict__ bhb,
    short* __restrict__ hB, short* __restrict__ ench, unsigned* __restrict__ ctrs) {
  __shared__ short lds_h[16384];  // 32KB: [64 kc8][32 b][8sh]
  const int tid = threadIdx.x, lane = tid & 63, wid = tid >> 6;
  const int l15 = lane & 15, lq = lane >> 4;
  const int w = blockIdx.x;
  const int gru = w >> 5, rr = w & 31, bg = rr >> 3, cw = rr & 7;
  const int J0 = (cw * 4 + wid) * 16, b0 = bg * 32;
  const short* Wg = gru ? Whb : Whf;
  const float* bb = gru ? bhb : bhf;
  const short* xpT = gru ? xpTb : xpTf;
  short* hBg = hB + (size_t)gru * 131072;
  unsigned* ctr = ctrs + (gru * 4 + bg);
  const f32x4 vz = {0.f, 0.f, 0.f, 0.f};

  s16x8 wfr[3][16];
#pragma unroll
  for (int g = 0; g < 3; ++g) {
    const short* wrp = Wg + (size_t)(g * 512 + J0 + l15) * 512 + lq * 8;
#pragma unroll
    for (int kc = 0; kc < 16; ++kc) wfr[g][kc] = *(const s16x8*)(wrp + kc * 32);
  }
  float bi[3][4];
#pragma unroll
  for (int g = 0; g < 3; ++g)
#pragma unroll
    for (int d = 0; d < 4; ++d) bi[g][d] = bb[g * 512 + J0 + lq * 4 + d];
  float hpv[2][4];
#pragma unroll
  for (int nt = 0; nt < 2; ++nt)
#pragma unroll
    for (int d = 0; d < 4; ++d) hpv[nt][d] = 0.f;

  for (int t = 0; t < 192; ++t) {
    if (t > 0) stage_h(hBg + ((t + 1) & 1) * 65536, lds_h, b0, tid);
    __syncthreads();
    f32x4 acc[3][2];
#pragma unroll
    for (int g = 0; g < 3; ++g)
#pragma unroll
      for (int nt = 0; nt < 2; ++nt) acc[g][nt] = vz;
    if (t > 0) {
#pragma unroll
      for (int kc = 0; kc < 16; ++kc) {
        const short* lp = lds_h + (size_t)((kc * 4 + lq) * 32 + l15) * 8;
        s16x8 f0 = *(const s16x8*)lp;
        s16x8 f1 = *(const s16x8*)(lp + 128);
#pragma unroll
        for (int g = 0; g < 3; ++g) {
          acc[g][0] = MFMA(wfr[g][kc], f0, acc[g][0]);
          acc[g][1] = MFMA(wfr[g][kc], f1, acc[g][1]);
        }
      }
    }
    const int tt = gru ? (191 - t) : t;
    short* hdst = hBg + (t & 1) * 65536;
    const short* xb = xpT + (size_t)tt * 1536 * 128;
#pragma unroll
    for (int nt = 0; nt < 2; ++nt) {
      const int b = b0 + nt * 16 + l15;
      s16x4 pk;
#pragma unroll
      for (int d = 0; d < 4; ++d) {
        const int ch = J0 + lq * 4 + d;
        float xr = b2f(xb[(size_t)ch * 128 + b]);
        float xz = b2f(xb[(size_t)(512 + ch) * 128 + b]);
        float xn = b2f(xb[(size_t)(1024 + ch) * 128 + b]);
        float hr = acc[0][nt][d] + bi[0][d];
        float hz = acc[1][nt][d] + bi[1][d];
        float hn = acc[2][nt][d] + bi[2][d];
        float rg = fsig(xr + hr);
        float zg = fsig(xz + hz);
        float nn = ftanh(xn + rg * hn);
        float hv = (1.f - zg) * nn + zg * hpv[nt][d];
        hpv[nt][d] = hv;
        pk[d] = f2b(hv);
      }
      const int chb = J0 + lq * 4;
      store_coh8(hdst + (((size_t)((chb >> 3) * 128 + b)) << 3) + (chb & 7), pk);
      if (t == 191) *(s16x4*)(ench + (size_t)gru * 65536 + (size_t)b * 512 + chb) = pk;
    }
    group_barrier(ctr, 8u * (unsigned)(t + 1));
  }
}

// ---------------- persistent decoder scan ----------------
// 64 WGs x 256 thr. WG w: bg=w>>4, w4=w&15. Wave wid: pairi=wid>>1, role=wid&1.
__global__ __launch_bounds__(256, 1) void dec_scan(
    const short* __restrict__ zpT, const short* __restrict__ Whd,
    const short* __restrict__ Wsd, const float* __restrict__ bhd,
    const float* __restrict__ h0f, short* __restrict__ hB,
    short* __restrict__ Hs, unsigned* __restrict__ ctrs) {
  __shared__ short lds_h[16384];           // 32KB staged h slice
  __shared__ float lxs[2][3][16][32];      // 12KB W_s partial exchange
  const int tid = threadIdx.x, lane = tid & 63, wid = tid >> 6;
  const int l15 = lane & 15, lq = lane >> 4;
  const int w = blockIdx.x;
  const int bg = w >> 4, w4 = w & 15;
  const int pairi = wid >> 1, role = wid & 1;
  const int J0 = (w4 * 2 + pairi) * 16, b0 = bg * 32;
  unsigned* ctr = ctrs + 8 + bg;
  const short* Wg = role ? Wsd : Whd;
  const f32x4 vz = {0.f, 0.f, 0.f, 0.f};

  s16x8 wfr[3][16];
#pragma unroll
  for (int g = 0; g < 3; ++g) {
    const short* wrp = Wg + (size_t)(g * 512 + J0 + l15) * 512 + lq * 8;
#pragma unroll
    for (int kc = 0; kc < 16; ++kc) wfr[g][kc] = *(const s16x8*)(wrp + kc * 32);
  }
  float bi[3][4];
  float hpv[2][4];
#pragma unroll
  for (int g = 0; g < 3; ++g)
#pragma unroll
    for (int d = 0; d < 4; ++d)
      bi[g][d] = (role == 0) ? bhd[g * 512 + J0 + lq * 4 + d] : 0.f;
#pragma unroll
  for (int nt = 0; nt < 2; ++nt)
#pragma unroll
    for (int d = 0; d < 4; ++d)
      hpv[nt][d] = (role == 0) ? h0f[(size_t)(b0 + nt * 16 + l15) * 512 + J0 + lq * 4 + d] : 0.f;

  for (int t = 0; t < 192; ++t) {
    stage_h(hB + ((t + 1) & 1) * 65536, lds_h, b0, tid);
    __syncthreads();
    f32x4 acc[3][2];
#pragma unroll
    for (int g = 0; g < 3; ++g)
#pragma unroll
      for (int nt = 0; nt < 2; ++nt) acc[g][nt] = vz;
    if (t > 0 || role == 0) {  // t=0: s=0 so W_s waves skip; h=dec_h0 prefilled in parity 1
#pragma unroll
      for (int kc = 0; kc < 16; ++kc) {
        const short* lp = lds_h + (size_t)((kc * 4 + lq) * 32 + l15) * 8;
        s16x8 f0 = *(const s16x8*)lp;
        s16x8 f1 = *(const s16x8*)(lp + 128);
#pragma unroll
        for (int g = 0; g < 3; ++g) {
          acc[g][0] = MFMA(wfr[g][kc], f0, acc[g][0]);
          acc[g][1] = MFMA(wfr[g][kc], f1, acc[g][1]);
        }
      }
    }
    if (role == 1) {
#pragma unroll
      for (int g = 0; g < 3; ++g)
#pragma unroll
        for (int nt = 0; nt < 2; ++nt)
#pragma unroll
          for (int d = 0; d < 4; ++d)
            lxs[pairi][g][lq * 4 + d][nt * 16 + l15] = acc[g][nt][d];
    }
    __syncthreads();
    if (role == 0) {
      short* hdst = hB + (t & 1) * 65536;
#pragma unroll
      for (int nt = 0; nt < 2; ++nt) {
        const int b = b0 + nt * 16 + l15;
        s16x4 pk;
#pragma unroll
        for (int d = 0; d < 4; ++d) {
          const int chl = lq * 4 + d, ch = J0 + chl;
          float xr = b2f(zpT[(size_t)ch * 128 + b]) + lxs[pairi][0][chl][nt * 16 + l15];
          float xz = b2f(zpT[(size_t)(512 + ch) * 128 + b]) + lxs[pairi][1][chl][nt * 16 + l15];
          float xn = b2f(zpT[(size_t)(1024 + ch) * 128 + b]) + lxs[pairi][2][chl][nt * 16 + l15];
          float hr = acc[0][nt][d] + bi[0][d];
          float hz = acc[1][nt][d] + bi[1][d];
          float hn = acc[2][nt][d] + bi[2][d];
          float rg = fsig(xr + hr);
          float zg = fsig(xz + hz);
          float nn = ftanh(xn + rg * hn);
          float hv = (1.f - zg) * nn + zg * hpv[nt][d];
          hpv[nt][d] = hv;
          pk[d] = f2b(hv);
        }
        const int chb = J0 + lq * 4;
        store_coh8(hdst + (((size_t)((chb >> 3) * 128 + b)) << 3) + (chb & 7), pk);
        *(s16x4*)(Hs + (size_t)(t * 128 + b) * 512 + chb) = pk;
      }
    }
    group_barrier(ctr, 16u * (unsigned)(t + 1));
  }
}

// ---------------- latent elementwise ----------------
__global__ void k_latent(const float* __restrict__ tmp, const float* __restrict__ b_mean,
                         const float* __restrict__ b_std, const float* __restrict__ eps_z,
                         float* __restrict__ out, short* __restrict__ zexp) {
  int i = blockIdx.x * 256 + threadIdx.x;
  if (i >= 32768) return;
  int c = i & 127, b = (i >> 7) & 127, g = i >> 14;
  float mp = tmp[(size_t)(g * 128 + b) * 256 + c] + b_mean[c];
  float sp = fsp(tmp[(size_t)(g * 128 + b) * 256 + 128 + c] + b_std[c]);
  float zv = eps_z[i] * sp + mp;
  out[i] = mp;
  out[32768 + i] = sp;
  out[65536 + i] = zv;
  zexp[b * 256 + g * 128 + c] = f2b(zv);
}

// ---------------- outputs elementwise ----------------
__global__ void k_preds(const float* __restrict__ tmp2, const float* __restrict__ b_dm,
                        const float* __restrict__ b_ds, const float* __restrict__ eps_y,
                        float* __restrict__ out) {
  int j = blockIdx.x * 256 + threadIdx.x;
  if (j >= 1572864) return;
  int c = j & 63;
  int row = j >> 6;
  float m = fsp(tmp2[(size_t)row * 128 + c] + b_dm[c]);
  float st = fsp(tmp2[(size_t)row * 128 + 64 + c] + b_ds[c]);
  out[98304 + j] = eps_y[j] * st + m;
  out[1671168 + j] = m;
  out[3244032 + j] = st;
}

// ---------------- launch ----------------
extern "C" void kernel_launch(void* const* d_in, const int* in_sizes, int n_in,
                              void* d_out, int out_size, void* d_ws, size_t ws_size,
                              hipStream_t stream) {
  (void)in_sizes; (void)n_in; (void)out_size; (void)ws_size;
  const float* x      = (const float*)d_in[0];
  const float* eps_z  = (const float*)d_in[2];
  const float* eps_y  = (const float*)d_in[3];
  const float* W_phi1 = (const float*)d_in[4];
  const float* b_phi1 = (const float*)d_in[5];
  const float* W_phi2 = (const float*)d_in[6];
  const float* b_phi2 = (const float*)d_in[7];
  const float* Wih_ef = (const float*)d_in[8];
  const float* bih_ef = (const float*)d_in[9];
  const float* Whh_ef = (const float*)d_in[10];
  const float* bhh_ef = (const float*)d_in[11];
  const float* Wih_eb = (const float*)d_in[12];
  const float* bih_eb = (const float*)d_in[13];
  const float* Whh_eb = (const float*)d_in[14];
  const float* bhh_eb = (const float*)d_in[15];
  const float* W_mean = (const float*)d_in[16];
  const float* b_mean = (const float*)d_in[17];
  const float* W_std  = (const float*)d_in[18];
  const float* b_std  = (const float*)d_in[19];
  const float* W_fh   = (const float*)d_in[20];
  const float* b_fh   = (const float*)d_in[21];
  const float* Wih_d  = (const float*)d_in[22];
  const float* bih_d  = (const float*)d_in[23];
  const float* Whh_d  = (const float*)d_in[24];
  const float* bhh_d  = (const float*)d_in[25];
  const float* W_dm   = (const float*)d_in[26];
  const float* b_dm   = (const float*)d_in[27];
  const float* W_ds   = (const float*)d_in[28];
  const float* b_ds   = (const float*)d_in[29];
  float* out = (float*)d_out;
  char* ws = (char*)d_ws;

  short* x16  = (short*)(ws + 0);
  short* C1   = (short*)(ws + 6291456);
  short* Hs   = (short*)(ws + 0);
  short* phi  = (short*)(ws + 31457280);
  float* tmp2 = (float*)(ws + 31457280);
  short* xpf  = (short*)(ws + 56623104);
  short* xpb  = (short*)(ws + 132120576);
  char*  wb   = ws + 207618048;
  short* w_phi1_16 = (short*)(wb + 0);
  short* w_phi2_16 = (short*)(wb + 131072);
  short* w_ihef = (short*)(wb + 655360);
  short* w_hhef = (short*)(wb + 2228224);
  short* w_iheb = (short*)(wb + 3801088);
  short* w_hheb = (short*)(wb + 5373952);
  short* w_ms   = (short*)(wb + 6946816);
  short* w_fh   = (short*)(wb + 7208960);
  short* w_z    = (short*)(wb + 7471104);
  short* w_s    = (short*)(wb + 8257536);
  short* w_hhd  = (short*)(wb + 9830400);
  short* w_out  = (short*)(wb + 11403264);
  short* hBe   = (short*)(ws + 219152384);
  short* ench  = (short*)(ws + 219676672);
  float* tmpms = (float*)(ws + 219938816);
  short* zexp  = (short*)(ws + 220200960);
  float* h0f   = (float*)(ws + 220266496);
  short* hBd   = (short*)(ws + 220528640);
  short* zpT   = (short*)(ws + 220790784);
  unsigned* ctr = (unsigned*)(ws + 221184000);

  hipMemsetAsync(ctr, 0, 256, stream);

  k_f2b<<<3072, 256, 0, stream>>>(x, x16, 3145728);
  k_f2b<<<64,   256, 0, stream>>>(W_phi1, w_phi1_16, 65536);
  k_f2b<<<256,  256, 0, stream>>>(W_phi2, w_phi2_16, 262144);
  k_f2b<<<768,  256, 0, stream>>>(Wih_ef, w_ihef, 786432);
  k_f2b<<<768,  256, 0, stream>>>(Whh_ef, w_hhef, 786432);
  k_f2b<<<768,  256, 0, stream>>>(Wih_eb, w_iheb, 786432);
  k_f2b<<<768,  256, 0, stream>>>(Whh_eb, w_hheb, 786432);
  k_f2b<<<64,   256, 0, stream>>>(W_mean, w_ms, 65536);
  k_f2b<<<64,   256, 0, stream>>>(W_std,  w_ms + 65536, 65536);
  k_f2b<<<128,  256, 0, stream>>>(W_fh, w_fh, 131072);
  k_f2b<<<768,  256, 0, stream>>>(Whh_d, w_hhd, 786432);
  k_f2b<<<32,   256, 0, stream>>>(W_dm, w_out, 32768);
  k_f2b<<<32,   256, 0, stream>>>(W_ds, w_out + 32768, 32768);
  k_f2bs<<<384, 256, 0, stream>>>(Wih_d, w_z, 256, 768, 0, 393216);
  k_f2bs<<<768, 256, 0, stream>>>(Wih_d, w_s, 512, 768, 256, 786432);

  kgemm<1><<<dim3(192, 4), 256, 0, stream>>>(x16, w_phi1_16, b_phi1, (float*)nullptr, C1, 24576, 512, 128);
  kgemm<1><<<dim3(192, 4), 256, 0, stream>>>(C1, w_phi2_16, b_phi2, (float*)nullptr, phi, 24576, 512, 512);
  kgemm<2><<<dim3(192, 12), 256, 0, stream>>>(phi, w_ihef, bih_ef, (float*)nullptr, xpf, 24576, 1536, 512);
  kgemm<2><<<dim3(192, 12), 256, 0, stream>>>(phi, w_iheb, bih_eb, (float*)nullptr, xpb, 24576, 1536, 512);
  enc_scan<<<64, 256, 0, stream>>>(xpf, xpb, w_hhef, w_hheb, bhh_ef, bhh_eb, hBe, ench, ctr);
  kgemm<0><<<dim3(2, 2), 256, 0, stream>>>(ench, w_ms, (const float*)nullptr, tmpms, (short*)nullptr, 256, 256, 512);
  k_latent<<<128, 256, 0, stream>>>(tmpms, b_mean, b_std, eps_z, out, zexp);
  kgemm<3><<<dim3(1, 4), 256, 0, stream>>>(zexp, w_fh, b_fh, h0f, hBd + 65536, 128, 512, 256);
  kgemm<2><<<dim3(1, 12), 256, 0, stream>>>(zexp, w_z, bih_d, (float*)nullptr, zpT, 128, 1536, 256);
  dec_scan<<<64, 256, 0, stream>>>(zpT, w_hhd, w_s, bhh_d, h0f, hBd, Hs, ctr);
  kgemm<0><<<dim3(192, 1), 256, 0, stream>>>(Hs, w_out, (const float*)nullptr, tmp2, (short*)nullptr, 24576, 128, 512);
  k_preds<<<6144, 256, 0, stream>>>(tmp2, b_dm, b_ds, eps_y, out);
}

// Round 4
// 2260.171 us; speedup vs baseline: 3.0160x; 1.5338x over previous
//
#include <hip/hip_runtime.h>
#include <stdint.h>

// ---------------- types & helpers ----------------
typedef __attribute__((ext_vector_type(4))) float    f32x4;
typedef __attribute__((ext_vector_type(8))) short    s16x8;
typedef __attribute__((ext_vector_type(4))) short    s16x4;
typedef __attribute__((ext_vector_type(4))) unsigned u32x4;
typedef __attribute__((ext_vector_type(8))) __bf16   bf16x8;

#define DEV __device__ __forceinline__

DEV float b2f(short h) {
  unsigned u = ((unsigned)(unsigned short)h) << 16;
  return __builtin_bit_cast(float, u);
}
DEV short f2b(float f) {
  unsigned u = __builtin_bit_cast(unsigned, f);
  u = (u + 0x7FFFu + ((u >> 16) & 1u)) >> 16;
  return (short)u;
}
DEV float fsig(float x) { return 1.0f / (1.0f + __expf(-x)); }
DEV float ftanh(float x) {
  x = fminf(fmaxf(x, -15.0f), 15.0f);
  float e = __expf(2.0f * x);
  return (e - 1.0f) / (e + 1.0f);
}
DEV float fsp(float x) { return (x > 20.0f) ? x : __logf(1.0f + __expf(x)); }

DEV f32x4 MFMA(s16x8 a, s16x8 b, f32x4 c) {
  return __builtin_amdgcn_mfma_f32_16x16x32_bf16(
      __builtin_bit_cast(bf16x8, a), __builtin_bit_cast(bf16x8, b), c, 0, 0, 0);
}
DEV void gload16(const void* g, void* l) {
  __builtin_amdgcn_global_load_lds(
      (const __attribute__((address_space(1))) unsigned*)g,
      (__attribute__((address_space(3))) unsigned*)l, 16, 0, 0);
}

// ---- cross-XCD coherent accesses: explicit sc0 sc1 (bypass L1+L2, hit LLC) ----
DEV s16x8 load_coh16(const short* p) {
  s16x8 r;
  asm volatile("global_load_dwordx4 %0, %1, off sc0 sc1" : "=v"(r) : "v"(p) : "memory");
  return r;
}
DEV void store_coh8(short* p, s16x4 v) {
  asm volatile("global_store_dwordx2 %0, %1, off sc0 sc1" :: "v"(p), "v"(v) : "memory");
}
DEV void store_flag(unsigned* p, unsigned v) {
  asm volatile("global_store_dword %0, %1, off sc0 sc1" :: "v"(p), "v"(v) : "memory");
}

// poll 8 flag dwords (32B) until min >= tgt
DEV void poll8(const unsigned* f, unsigned tgt) {
  unsigned gd = 0;
  for (;;) {
    u32x4 a, b;
    asm volatile("global_load_dwordx4 %0, %2, off sc0 sc1\n\t"
                 "global_load_dwordx4 %1, %2, off offset:16 sc0 sc1\n\t"
                 "s_waitcnt vmcnt(0)"
                 : "=v"(a), "=v"(b) : "v"(f) : "memory");
    unsigned m = a[0];
    m = a[1] < m ? a[1] : m; m = a[2] < m ? a[2] : m; m = a[3] < m ? a[3] : m;
    m = b[0] < m ? b[0] : m; m = b[1] < m ? b[1] : m;
    m = b[2] < m ? b[2] : m; m = b[3] < m ? b[3] : m;
    if (m >= tgt) return;
    if (++gd > (1u << 17)) return;  // deadlock escape
  }
}
// poll 16 flag dwords (64B)
DEV void poll16(const unsigned* f, unsigned tgt) {
  unsigned gd = 0;
  for (;;) {
    u32x4 a, b, c, d;
    asm volatile("global_load_dwordx4 %0, %4, off sc0 sc1\n\t"
                 "global_load_dwordx4 %1, %4, off offset:16 sc0 sc1\n\t"
                 "global_load_dwordx4 %2, %4, off offset:32 sc0 sc1\n\t"
                 "global_load_dwordx4 %3, %4, off offset:48 sc0 sc1\n\t"
                 "s_waitcnt vmcnt(0)"
                 : "=v"(a), "=v"(b), "=v"(c), "=v"(d) : "v"(f) : "memory");
    unsigned m = a[0];
    m = a[1] < m ? a[1] : m; m = a[2] < m ? a[2] : m; m = a[3] < m ? a[3] : m;
    m = b[0] < m ? b[0] : m; m = b[1] < m ? b[1] : m; m = b[2] < m ? b[2] : m; m = b[3] < m ? b[3] : m;
    m = c[0] < m ? c[0] : m; m = c[1] < m ? c[1] : m; m = c[2] < m ? c[2] : m; m = c[3] < m ? c[3] : m;
    m = d[0] < m ? d[0] : m; m = d[1] < m ? d[1] : m; m = d[2] < m ? d[2] : m; m = d[3] < m ? d[3] : m;
    if (m >= tgt) return;
    if (++gd > (1u << 17)) return;
  }
}

// load this wave's 32 B-fragments directly from coherent h buffer
DEV void load_h_frags(const short* hsrc, int lq, int l15, int b0, s16x8 hb[16][2]) {
#pragma unroll
  for (int kc = 0; kc < 16; ++kc)
#pragma unroll
    for (int nt = 0; nt < 2; ++nt)
      hb[kc][nt] = load_coh16(hsrc + ((size_t)((kc * 4 + lq) * 128 + b0 + nt * 16 + l15) << 3));
}

// ---------------- fp32 -> bf16 converts ----------------
__global__ void k_f2b(const float* __restrict__ s, short* __restrict__ d, int n) {
  int i = (blockIdx.x * 256 + threadIdx.x) * 4;
  if (i >= n) return;
  float4 v = *(const float4*)(s + i);
  s16x4 o; o[0] = f2b(v.x); o[1] = f2b(v.y); o[2] = f2b(v.z); o[3] = f2b(v.w);
  *(s16x4*)(d + i) = o;
}

__global__ void k_f2bs(const float* __restrict__ s, short* __restrict__ d,
                       int cols, int sstr, int soff, int total) {
  int i = (blockIdx.x * 256 + threadIdx.x) * 4;
  if (i >= total) return;
  int r = i / cols, c = i - r * cols;
  float4 v = *(const float4*)(s + (size_t)r * sstr + soff + c);
  s16x4 o; o[0] = f2b(v.x); o[1] = f2b(v.y); o[2] = f2b(v.z); o[3] = f2b(v.w);
  *(s16x4*)(d + i) = o;
}

// ---------------- generic bf16 MFMA GEMM, 128x128 tile, BK=64 ----------------
template <int EPI>
__global__ __launch_bounds__(256) void kgemm(
    const short* __restrict__ A, const short* __restrict__ W,
    const float* __restrict__ bias, float* __restrict__ outF,
    short* __restrict__ outB, int M, int N, int K) {
  __shared__ short lA[8192];
  __shared__ short lB[8192];
  const int tid = threadIdx.x, lane = tid & 63, wid = tid >> 6;
  const int l15 = lane & 15, lq = lane >> 4;
  const int m0 = blockIdx.x * 128, n0 = blockIdx.y * 128;
  const int wr2 = wid >> 1, wc2 = wid & 1;
  const f32x4 vz = {0.f, 0.f, 0.f, 0.f};
  f32x4 acc[4][4];
#pragma unroll
  for (int i = 0; i < 4; ++i)
#pragma unroll
    for (int j = 0; j < 4; ++j) acc[i][j] = vz;
  const int Kb = K * 2;
  const int nkt = K >> 6;
  const int srow = lane >> 3, sk = (lane & 7) * 16;
  const char* gA = (const char*)A;
  const char* gW = (const char*)W;
  for (int kt = 0; kt < nkt; ++kt) {
    __syncthreads();
#pragma unroll
    for (int i = 0; i < 4; ++i) {
      const int c = wid * 4 + i;
      gload16(gA + (size_t)(m0 + c * 8 + srow) * Kb + kt * 128 + sk, (char*)lA + c * 1024);
      gload16(gW + (size_t)(n0 + c * 8 + srow) * Kb + kt * 128 + sk, (char*)lB + c * 1024);
    }
    __syncthreads();
#pragma unroll
    for (int kc = 0; kc < 2; ++kc) {
      s16x8 af[4], bf[4];
#pragma unroll
      for (int mt = 0; mt < 4; ++mt)
        af[mt] = *(const s16x8*)((const char*)lA + (wr2 * 64 + mt * 16 + l15) * 128 + kc * 64 + lq * 16);
#pragma unroll
      for (int nt = 0; nt < 4; ++nt)
        bf[nt] = *(const s16x8*)((const char*)lB + (wc2 * 64 + nt * 16 + l15) * 128 + kc * 64 + lq * 16);
#pragma unroll
      for (int mt = 0; mt < 4; ++mt)
#pragma unroll
        for (int nt = 0; nt < 4; ++nt)
          acc[mt][nt] = MFMA(af[mt], bf[nt], acc[mt][nt]);
    }
  }
#pragma unroll
  for (int mt = 0; mt < 4; ++mt) {
#pragma unroll
    for (int nt = 0; nt < 4; ++nt) {
      const int col = n0 + wc2 * 64 + nt * 16 + l15;
      const int rl = wr2 * 64 + mt * 16 + lq * 4;
      const int row = m0 + rl;
      const float bv = bias ? bias[col] : 0.f;
      if (EPI == 0) {
#pragma unroll
        for (int d = 0; d < 4; ++d) outF[(size_t)(row + d) * N + col] = acc[mt][nt][d] + bv;
      } else if (EPI == 1) {
#pragma unroll
        for (int d = 0; d < 4; ++d) {
          float v = acc[mt][nt][d] + bv;
          v = v > 0.f ? v : 0.f;
          outB[(size_t)(row + d) * N + col] = f2b(v);
        }
      } else if (EPI == 2) {
        s16x4 pk;
#pragma unroll
        for (int d = 0; d < 4; ++d) pk[d] = f2b(acc[mt][nt][d] + bv);
        *(s16x4*)(outB + ((size_t)blockIdx.x * N + col) * 128 + rl) = pk;
      } else {
#pragma unroll
        for (int d = 0; d < 4; ++d) {
          float v = ftanh(acc[mt][nt][d] + bv);
          outF[(size_t)(row + d) * N + col] = v;
          outB[((size_t)(col >> 3) * 128 + (row + d)) * 8 + (col & 7)] = f2b(v);
        }
      }
    }
  }
}

// ---------------- persistent encoder scan (fwd + bwd GRU) ----------------
// 64 WGs x 256 thr. WG w: gru=w>>5, bg=(w&31)>>3, cw=w&7. Wave wid: col-tile cw*4+wid.
// Sync: per-WG flag words (256B-padded per group), all-thread polling, no atomics.
// h exchange: direct coherent loads into register B-fragments (no LDS staging).
__global__ __launch_bounds__(256, 1) void enc_scan(
    const short* __restrict__ xpTf, const short* __restrict__ xpTb,
    const short* __restrict__ Whf, const short* __restrict__ Whb,
    const float* __restrict__ bhf, const float* __restrict__ bhb,
    short* __restrict__ hB, short* __restrict__ ench, unsigned* __restrict__ flags) {
  const int tid = threadIdx.x, lane = tid & 63, wid = tid >> 6;
  const int l15 = lane & 15, lq = lane >> 4;
  const int w = blockIdx.x;
  const int gru = w >> 5, rr = w & 31, bg = rr >> 3, cw = rr & 7;
  const int J0 = (cw * 4 + wid) * 16, b0 = bg * 32;
  const short* Wg = gru ? Whb : Whf;
  const float* bb = gru ? bhb : bhf;
  const short* xpT = gru ? xpTb : xpTf;
  short* hBg = hB + (size_t)gru * 131072;
  unsigned* gfl = flags + (gru * 4 + bg) * 64;  // 8 dwords used, 256B stride
  const f32x4 vz = {0.f, 0.f, 0.f, 0.f};

  s16x8 wfr[3][16];
#pragma unroll
  for (int g = 0; g < 3; ++g) {
    const short* wrp = Wg + (size_t)(g * 512 + J0 + l15) * 512 + lq * 8;
#pragma unroll
    for (int kc = 0; kc < 16; ++kc) wfr[g][kc] = *(const s16x8*)(wrp + kc * 32);
  }
  float bi[3][4];
#pragma unroll
  for (int g = 0; g < 3; ++g)
#pragma unroll
    for (int d = 0; d < 4; ++d) bi[g][d] = bb[g * 512 + J0 + lq * 4 + d];
  float hpv[2][4];
#pragma unroll
  for (int nt = 0; nt < 2; ++nt)
#pragma unroll
    for (int d = 0; d < 4; ++d) hpv[nt][d] = 0.f;

  // prefetch xp(0) into registers
  short xpv[3][2][4];
  {
    const short* xb = xpT + (size_t)(gru ? 191 : 0) * 1536 * 128;
#pragma unroll
    for (int g = 0; g < 3; ++g)
#pragma unroll
      for (int nt = 0; nt < 2; ++nt)
#pragma unroll
        for (int d = 0; d < 4; ++d)
          xpv[g][nt][d] = xb[(size_t)(g * 512 + J0 + lq * 4 + d) * 128 + b0 + nt * 16 + l15];
  }

  for (int t = 0; t < 192; ++t) {
    f32x4 acc[3][2];
#pragma unroll
    for (int g = 0; g < 3; ++g)
#pragma unroll
      for (int nt = 0; nt < 2; ++nt) acc[g][nt] = vz;
    if (t > 0) {
      poll8(gfl, (unsigned)t);
      s16x8 hb[16][2];
      load_h_frags(hBg + ((t + 1) & 1) * 65536, lq, l15, b0, hb);
      asm volatile("s_waitcnt vmcnt(0)" ::: "memory");
      __builtin_amdgcn_sched_barrier(0);
#pragma unroll
      for (int kc = 0; kc < 16; ++kc)
#pragma unroll
        for (int g = 0; g < 3; ++g) {
          acc[g][0] = MFMA(wfr[g][kc], hb[kc][0], acc[g][0]);
          acc[g][1] = MFMA(wfr[g][kc], hb[kc][1], acc[g][1]);
        }
    }
    short* hdst = hBg + (t & 1) * 65536;
#pragma unroll
    for (int nt = 0; nt < 2; ++nt) {
      const int b = b0 + nt * 16 + l15;
      s16x4 pk;
#pragma unroll
      for (int d = 0; d < 4; ++d) {
        float xr = b2f(xpv[0][nt][d]);
        float xz = b2f(xpv[1][nt][d]);
        float xn = b2f(xpv[2][nt][d]);
        float hr = acc[0][nt][d] + bi[0][d];
        float hz = acc[1][nt][d] + bi[1][d];
        float hn = acc[2][nt][d] + bi[2][d];
        float rg = fsig(xr + hr);
        float zg = fsig(xz + hz);
        float nn = ftanh(xn + rg * hn);
        float hv = (1.f - zg) * nn + zg * hpv[nt][d];
        hpv[nt][d] = hv;
        pk[d] = f2b(hv);
      }
      const int chb = J0 + lq * 4;
      store_coh8(hdst + (((size_t)((chb >> 3) * 128 + b)) << 3) + (chb & 7), pk);
      if (t == 191) *(s16x4*)(ench + (size_t)gru * 65536 + (size_t)b * 512 + chb) = pk;
    }
    // prefetch xp(t+1) (overlaps store-drain + flag + poll of next step)
    {
      const int tp = (t < 191) ? t + 1 : 191;
      const int tt = gru ? (191 - tp) : tp;
      const short* xb = xpT + (size_t)tt * 1536 * 128;
#pragma unroll
      for (int g = 0; g < 3; ++g)
#pragma unroll
        for (int nt = 0; nt < 2; ++nt)
#pragma unroll
          for (int d = 0; d < 4; ++d)
            xpv[g][nt][d] = xb[(size_t)(g * 512 + J0 + lq * 4 + d) * 128 + b0 + nt * 16 + l15];
    }
    asm volatile("s_waitcnt vmcnt(0)" ::: "memory");
    __syncthreads();
    if (tid == 0) store_flag(gfl + cw, (unsigned)(t + 1));
  }
}

// ---------------- persistent decoder scan ----------------
// 64 WGs x 256 thr. WG w: bg=w>>4, w4=w&15. Wave wid: pairi=wid>>1, role=wid&1.
__global__ __launch_bounds__(256, 1) void dec_scan(
    const short* __restrict__ zpT, const short* __restrict__ Whd,
    const short* __restrict__ Wsd, const float* __restrict__ bhd,
    const float* __restrict__ h0f, short* __restrict__ hB,
    short* __restrict__ Hs, unsigned* __restrict__ flags) {
  __shared__ float lxs[2][3][16][32];  // W_s partial exchange
  const int tid = threadIdx.x, lane = tid & 63, wid = tid >> 6;
  const int l15 = lane & 15, lq = lane >> 4;
  const int w = blockIdx.x;
  const int bg = w >> 4, w4 = w & 15;
  const int pairi = wid >> 1, role = wid & 1;
  const int J0 = (w4 * 2 + pairi) * 16, b0 = bg * 32;
  unsigned* gfl = flags + 512 + bg * 64;  // 16 dwords used, 256B stride
  const short* Wg = role ? Wsd : Whd;
  const f32x4 vz = {0.f, 0.f, 0.f, 0.f};

  s16x8 wfr[3][16];
#pragma unroll
  for (int g = 0; g < 3; ++g) {
    const short* wrp = Wg + (size_t)(g * 512 + J0 + l15) * 512 + lq * 8;
#pragma unroll
    for (int kc = 0; kc < 16; ++kc) wfr[g][kc] = *(const s16x8*)(wrp + kc * 32);
  }
  float bi[3][4];
  float hpv[2][4];
#pragma unroll
  for (int g = 0; g < 3; ++g)
#pragma unroll
    for (int d = 0; d < 4; ++d)
      bi[g][d] = (role == 0) ? bhd[g * 512 + J0 + lq * 4 + d] : 0.f;
#pragma unroll
  for (int nt = 0; nt < 2; ++nt)
#pragma unroll
    for (int d = 0; d < 4; ++d)
      hpv[nt][d] = (role == 0) ? h0f[(size_t)(b0 + nt * 16 + l15) * 512 + J0 + lq * 4 + d] : 0.f;

  // z_proj is t-invariant: preload once
  short zpv[3][2][4];
#pragma unroll
  for (int g = 0; g < 3; ++g)
#pragma unroll
    for (int nt = 0; nt < 2; ++nt)
#pragma unroll
      for (int d = 0; d < 4; ++d)
        zpv[g][nt][d] = zpT[(size_t)(g * 512 + J0 + lq * 4 + d) * 128 + b0 + nt * 16 + l15];

  for (int t = 0; t < 192; ++t) {
    f32x4 acc[3][2];
#pragma unroll
    for (int g = 0; g < 3; ++g)
#pragma unroll
      for (int nt = 0; nt < 2; ++nt) acc[g][nt] = vz;
    if (t > 0) poll16(gfl, (unsigned)t);
    const bool doB = (t > 0) || (role == 0);  // t=0: s=0 so W_s waves skip
    if (doB) {
      s16x8 hb[16][2];
      load_h_frags(hB + ((t + 1) & 1) * 65536, lq, l15, b0, hb);
      asm volatile("s_waitcnt vmcnt(0)" ::: "memory");
      __builtin_amdgcn_sched_barrier(0);
#pragma unroll
      for (int kc = 0; kc < 16; ++kc)
#pragma unroll
        for (int g = 0; g < 3; ++g) {
          acc[g][0] = MFMA(wfr[g][kc], hb[kc][0], acc[g][0]);
          acc[g][1] = MFMA(wfr[g][kc], hb[kc][1], acc[g][1]);
        }
    }
    if (role == 1) {
#pragma unroll
      for (int g = 0; g < 3; ++g)
#pragma unroll
        for (int nt = 0; nt < 2; ++nt)
#pragma unroll
          for (int d = 0; d < 4; ++d)
            lxs[pairi][g][lq * 4 + d][nt * 16 + l15] = acc[g][nt][d];
    }
    __syncthreads();
    if (role == 0) {
      short* hdst = hB + (t & 1) * 65536;
#pragma unroll
      for (int nt = 0; nt < 2; ++nt) {
        const int b = b0 + nt * 16 + l15;
        s16x4 pk;
#pragma unroll
        for (int d = 0; d < 4; ++d) {
          const int chl = lq * 4 + d;
          float xr = b2f(zpv[0][nt][d]) + lxs[pairi][0][chl][nt * 16 + l15];
          float xz = b2f(zpv[1][nt][d]) + lxs[pairi][1][chl][nt * 16 + l15];
          float xn = b2f(zpv[2][nt][d]) + lxs[pairi][2][chl][nt * 16 + l15];
          float hr = acc[0][nt][d] + bi[0][d];
          float hz = acc[1][nt][d] + bi[1][d];
          float hn = acc[2][nt][d] + bi[2][d];
          float rg = fsig(xr + hr);
          float zg = fsig(xz + hz);
          float nn = ftanh(xn + rg * hn);
          float hv = (1.f - zg) * nn + zg * hpv[nt][d];
          hpv[nt][d] = hv;
          pk[d] = f2b(hv);
        }
        const int chb = J0 + lq * 4;
        store_coh8(hdst + (((size_t)((chb >> 3) * 128 + b)) << 3) + (chb & 7), pk);
        *(s16x4*)(Hs + (size_t)(t * 128 + b) * 512 + chb) = pk;
      }
    }
    asm volatile("s_waitcnt vmcnt(0)" ::: "memory");
    __syncthreads();
    if (tid == 0) store_flag(gfl + w4, (unsigned)(t + 1));
  }
}

// ---------------- latent elementwise ----------------
__global__ void k_latent(const float* __restrict__ tmp, const float* __restrict__ b_mean,
                         const float* __restrict__ b_std, const float* __restrict__ eps_z,
                         float* __restrict__ out, short* __restrict__ zexp) {
  int i = blockIdx.x * 256 + threadIdx.x;
  if (i >= 32768) return;
  int c = i & 127, b = (i >> 7) & 127, g = i >> 14;
  float mp = tmp[(size_t)(g * 128 + b) * 256 + c] + b_mean[c];
  float sp = fsp(tmp[(size_t)(g * 128 + b) * 256 + 128 + c] + b_std[c]);
  float zv = eps_z[i] * sp + mp;
  out[i] = mp;
  out[32768 + i] = sp;
  out[65536 + i] = zv;
  zexp[b * 256 + g * 128 + c] = f2b(zv);
}

// ---------------- outputs elementwise ----------------
__global__ void k_preds(const float* __restrict__ tmp2, const float* __restrict__ b_dm,
                        const float* __restrict__ b_ds, const float* __restrict__ eps_y,
                        float* __restrict__ out) {
  int j = blockIdx.x * 256 + threadIdx.x;
  if (j >= 1572864) return;
  int c = j & 63;
  int row = j >> 6;
  float m = fsp(tmp2[(size_t)row * 128 + c] + b_dm[c]);
  float st = fsp(tmp2[(size_t)row * 128 + 64 + c] + b_ds[c]);
  out[98304 + j] = eps_y[j] * st + m;
  out[1671168 + j] = m;
  out[3244032 + j] = st;
}

// ---------------- launch ----------------
extern "C" void kernel_launch(void* const* d_in, const int* in_sizes, int n_in,
                              void* d_out, int out_size, void* d_ws, size_t ws_size,
                              hipStream_t stream) {
  (void)in_sizes; (void)n_in; (void)out_size; (void)ws_size;
  const float* x      = (const float*)d_in[0];
  const float* eps_z  = (const float*)d_in[2];
  const float* eps_y  = (const float*)d_in[3];
  const float* W_phi1 = (const float*)d_in[4];
  const float* b_phi1 = (const float*)d_in[5];
  const float* W_phi2 = (const float*)d_in[6];
  const float* b_phi2 = (const float*)d_in[7];
  const float* Wih_ef = (const float*)d_in[8];
  const float* bih_ef = (const float*)d_in[9];
  const float* Whh_ef = (const float*)d_in[10];
  const float* bhh_ef = (const float*)d_in[11];
  const float* Wih_eb = (const float*)d_in[12];
  const float* bih_eb = (const float*)d_in[13];
  const float* Whh_eb = (const float*)d_in[14];
  const float* bhh_eb = (const float*)d_in[15];
  const float* W_mean = (const float*)d_in[16];
  const float* b_mean = (const float*)d_in[17];
  const float* W_std  = (const float*)d_in[18];
  const float* b_std  = (const float*)d_in[19];
  const float* W_fh   = (const float*)d_in[20];
  const float* b_fh   = (const float*)d_in[21];
  const float* Wih_d  = (const float*)d_in[22];
  const float* bih_d  = (const float*)d_in[23];
  const float* Whh_d  = (const float*)d_in[24];
  const float* bhh_d  = (const float*)d_in[25];
  const float* W_dm   = (const float*)d_in[26];
  const float* b_dm   = (const float*)d_in[27];
  const float* W_ds   = (const float*)d_in[28];
  const float* b_ds   = (const float*)d_in[29];
  float* out = (float*)d_out;
  char* ws = (char*)d_ws;

  short* x16  = (short*)(ws + 0);
  short* C1   = (short*)(ws + 6291456);
  short* Hs   = (short*)(ws + 0);
  short* phi  = (short*)(ws + 31457280);
  float* tmp2 = (float*)(ws + 31457280);
  short* xpf  = (short*)(ws + 56623104);
  short* xpb  = (short*)(ws + 132120576);
  char*  wb   = ws + 207618048;
  short* w_phi1_16 = (short*)(wb + 0);
  short* w_phi2_16 = (short*)(wb + 131072);
  short* w_ihef = (short*)(wb + 655360);
  short* w_hhef = (short*)(wb + 2228224);
  short* w_iheb = (short*)(wb + 3801088);
  short* w_hheb = (short*)(wb + 5373952);
  short* w_ms   = (short*)(wb + 6946816);
  short* w_fh   = (short*)(wb + 7208960);
  short* w_z    = (short*)(wb + 7471104);
  short* w_s    = (short*)(wb + 8257536);
  short* w_hhd  = (short*)(wb + 9830400);
  short* w_out  = (short*)(wb + 11403264);
  short* hBe   = (short*)(ws + 219152384);
  short* ench  = (short*)(ws + 219676672);
  float* tmpms = (float*)(ws + 219938816);
  short* zexp  = (short*)(ws + 220200960);
  float* h0f   = (float*)(ws + 220266496);
  short* hBd   = (short*)(ws + 220528640);
  short* zpT   = (short*)(ws + 220790784);
  unsigned* flags = (unsigned*)(ws + 221184000);

  hipMemsetAsync(flags, 0, 4096, stream);

  k_f2b<<<3072, 256, 0, stream>>>(x, x16, 3145728);
  k_f2b<<<64,   256, 0, stream>>>(W_phi1, w_phi1_16, 65536);
  k_f2b<<<256,  256, 0, stream>>>(W_phi2, w_phi2_16, 262144);
  k_f2b<<<768,  256, 0, stream>>>(Wih_ef, w_ihef, 786432);
  k_f2b<<<768,  256, 0, stream>>>(Whh_ef, w_hhef, 786432);
  k_f2b<<<768,  256, 0, stream>>>(Wih_eb, w_iheb, 786432);
  k_f2b<<<768,  256, 0, stream>>>(Whh_eb, w_hheb, 786432);
  k_f2b<<<64,   256, 0, stream>>>(W_mean, w_ms, 65536);
  k_f2b<<<64,   256, 0, stream>>>(W_std,  w_ms + 65536, 65536);
  k_f2b<<<128,  256, 0, stream>>>(W_fh, w_fh, 131072);
  k_f2b<<<768,  256, 0, stream>>>(Whh_d, w_hhd, 786432);
  k_f2b<<<32,   256, 0, stream>>>(W_dm, w_out, 32768);
  k_f2b<<<32,   256, 0, stream>>>(W_ds, w_out + 32768, 32768);
  k_f2bs<<<384, 256, 0, stream>>>(Wih_d, w_z, 256, 768, 0, 393216);
  k_f2bs<<<768, 256, 0, stream>>>(Wih_d, w_s, 512, 768, 256, 786432);

  kgemm<1><<<dim3(192, 4), 256, 0, stream>>>(x16, w_phi1_16, b_phi1, (float*)nullptr, C1, 24576, 512, 128);
  kgemm<1><<<dim3(192, 4), 256, 0, stream>>>(C1, w_phi2_16, b_phi2, (float*)nullptr, phi, 24576, 512, 512);
  kgemm<2><<<dim3(192, 12), 256, 0, stream>>>(phi, w_ihef, bih_ef, (float*)nullptr, xpf, 24576, 1536, 512);
  kgemm<2><<<dim3(192, 12), 256, 0, stream>>>(phi, w_iheb, bih_eb, (float*)nullptr, xpb, 24576, 1536, 512);
  enc_scan<<<64, 256, 0, stream>>>(xpf, xpb, w_hhef, w_hheb, bhh_ef, bhh_eb, hBe, ench, flags);
  kgemm<0><<<dim3(2, 2), 256, 0, stream>>>(ench, w_ms, (const float*)nullptr, tmpms, (short*)nullptr, 256, 256, 512);
  k_latent<<<128, 256, 0, stream>>>(tmpms, b_mean, b_std, eps_z, out, zexp);
  kgemm<3><<<dim3(1, 4), 256, 0, stream>>>(zexp, w_fh, b_fh, h0f, hBd + 65536, 128, 512, 256);
  kgemm<2><<<dim3(1, 12), 256, 0, stream>>>(zexp, w_z, bih_d, (float*)nullptr, zpT, 128, 1536, 256);
  dec_scan<<<64, 256, 0, stream>>>(zpT, w_hhd, w_s, bhh_d, h0f, hBd, Hs, flags);
  kgemm<0><<<dim3(192, 1), 256, 0, stream>>>(Hs, w_out, (const float*)nullptr, tmp2, (short*)nullptr, 24576, 128, 512);
  k_preds<<<6144, 256, 0, stream>>>(tmp2, b_dm, b_ds, eps_y, out);
}